// Round 12
// baseline (1248.918 us; speedup 1.0000x reference)
//
#include <hip/hip_runtime.h>

#define T_SEQ   1024
#define INDIM   6
#define HDIM    64
#define NPRED   10
#define CHNK    128
#define S0      104      // LDS row stride (elements) for A-operand buffers
#define NROWS   16       // batch rows per workgroup (grid 256 = 1 block/CU)

typedef __bf16         bf16x8 __attribute__((ext_vector_type(8)));
typedef float          f32x4  __attribute__((ext_vector_type(4)));
typedef unsigned short us4    __attribute__((ext_vector_type(4)));

#define MFMA16(a, b, c) __builtin_amdgcn_mfma_f32_16x16x32_bf16((a), (b), (c), 0, 0, 0)

static __device__ __forceinline__ float bf2f(unsigned short b) {
  union { unsigned int u; float f; } v; v.u = ((unsigned int)b) << 16; return v.f;
}
static __device__ __forceinline__ unsigned short f2bf(float f) {
  union { float f; unsigned int u; } v; v.f = f;
  unsigned int r = v.u + 0x7FFFu + ((v.u >> 16) & 1u);
  return (unsigned short)(r >> 16);
}

// r11 skeleton widened to 1024 threads / 16 waves (4 per SIMD), 1 block/CU.
// Engine A (L0) = waves 0-7, engine B (L1, lag 1) = waves 8-15. Wave-pairs
// (2t, 2t+1) share unit tile t: both issue the gate MFMAs (redundant, MFMA
// pipe has headroom), activation rows split by pair member (2 cells/lane).
// Same single barrier per encoder step; combined-rcp cell update (r11).
template <bool F32>
__global__ __launch_bounds__(1024, 1)
void lstm2_pipe(const void* __restrict__ xv,
                const void* __restrict__ Wih0v,
                const void* __restrict__ Whh0v,
                const void* __restrict__ bih0v,
                const void* __restrict__ bhh0v,
                const void* __restrict__ Wih1v,
                const void* __restrict__ Whh1v,
                const void* __restrict__ bih1v,
                const void* __restrict__ bhh1v,
                const void* __restrict__ fcwv,
                const void* __restrict__ fcbv,
                void* __restrict__ outv)
{
  // ---- dtype sniff (uniform) ----
  {
    const unsigned short* w0u = (const unsigned short*)Wih0v;
    int votes = 0;
#pragma unroll
    for (int i = 0; i < 16; ++i) {
      const unsigned e = (w0u[2 * i] >> 7) & 0xFF;
      votes += (e >= 0x80 || e <= 0x40) ? 1 : 0;
    }
    if ((votes >= 4) != F32) return;
  }

  // A0[b]: [row][k]: k 0..63 = h0, 64..69 = x, 70..95 zero pad. A1[b]: h1.
  __shared__ __align__(16) unsigned short A0[2][NROWS * S0];
  __shared__ __align__(16) unsigned short A1[2][NROWS * S0];
  __shared__ __align__(16) unsigned short XB[NROWS * CHNK * INDIM];
  __shared__ __align__(16) unsigned short FCW[INDIM * HDIM];
  __shared__ float FCB[INDIM];

  const int tid   = threadIdx.x;
  const int lane  = tid & 63;
  const int wave  = tid >> 6;          // 0..15
  const bool isA  = (wave < 8);
  const int  sub  = wave & 1;          // pair member: act rows r in {2sub, 2sub+1}
  const int  wv4  = (wave >> 1) & 3;   // unit tile within engine
  const int  q    = lane >> 4;
  const int  n    = lane & 15;
  const int  u    = 16 * wv4 + n;
  const int rbase = blockIdx.x * NROWS;

  {
    unsigned short* p0 = &A0[0][0];
    unsigned short* p1 = &A1[0][0];
    for (int i = tid; i < 2 * NROWS * S0; i += 1024) { p0[i] = 0; p1[i] = 0; }
  }
  for (int i = tid; i < INDIM * HDIM; i += 1024) {
    if constexpr (F32) FCW[i] = f2bf(((const float*)fcwv)[i]);
    else               FCW[i] = ((const unsigned short*)fcwv)[i];
  }
  if (tid < INDIM) {
    if constexpr (F32) FCB[tid] = ((const float*)fcbv)[tid];
    else               FCB[tid] = bf2f(((const unsigned short*)fcbv)[tid]);
  }

  auto ld1 = [&](const void* p, int i) -> float {
    if constexpr (F32) return ((const float*)p)[i];
    else               return bf2f(((const unsigned short*)p)[i]);
  };
  auto ld8 = [&](const void* W, int off) -> bf16x8 {
    union { unsigned short us[8]; bf16x8 v; } t;
    if constexpr (F32) {
      const float* p = (const float*)W + off;
#pragma unroll
      for (int j = 0; j < 8; ++j) t.us[j] = f2bf(p[j]);
    } else {
      t.v = *(const bf16x8*)((const unsigned short*)W + off);
    }
    return t.v;
  };

  auto load_chunk = [&](int t0c) {
    if constexpr (F32) {
      const char* xb = (const char*)xv;
      for (int c = tid; c < NROWS * 192; c += 1024) {
        const int row = c / 192;
        const int off = c - row * 192;
        const float4 v = *(const float4*)(xb + (size_t)(rbase + row) * (T_SEQ * INDIM * 4)
                                             + (size_t)t0c * (INDIM * 4) + (size_t)off * 16);
        us4 o;
        o.x = f2bf(v.x); o.y = f2bf(v.y); o.z = f2bf(v.z); o.w = f2bf(v.w);
        *(us4*)((char*)XB + (size_t)c * 8) = o;
      }
    } else {
      const char* xb = (const char*)xv;
      for (int c = tid; c < NROWS * 96; c += 1024) {
        const int row = c / 96;
        const int off = c - row * 96;
        const int4 v = *(const int4*)(xb + (size_t)(rbase + row) * (T_SEQ * INDIM * 2)
                                         + (size_t)t0c * (INDIM * 2) + (size_t)off * 16);
        *(int4*)((char*)XB + (size_t)c * 16) = v;
      }
    }
  };

  load_chunk(0);
  __syncthreads();

  const int xrow   = tid / INDIM;                 // valid for tid < 96 (A waves 0,1)
  const int xk     = tid - xrow * INDIM;
  const int xWrOff = xrow * S0 + HDIM + xk;
  const int xbBase = xrow * (CHNK * INDIM) + xk;

  if (tid < 96) A0[0][xWrOff] = XB[xbBase];       // x_0
  __syncthreads();

  const int aOff = n * S0 + 8 * q;   // A-frag: row m = n, k = 8q..8q+7 (+32*s)
  const int hOff = (4 * q) * S0 + u; // C-layout write: rows 4q+r, col u

  float cc[2] = {0.f, 0.f};          // this wave's two cells (rows 4q+2sub+rr)

  // Combined-rcp LSTM cell update on this wave's two rows (r = 2sub+rr).
  auto act2 = [&](const f32x4 gI, const f32x4 gF, const f32x4 gG, const f32x4 gO,
                  unsigned short* dst) {
#pragma unroll
    for (int rr = 0; rr < 2; ++rr) {
      const int r = 2 * sub + rr;
      const float Ae = __builtin_amdgcn_exp2f(gF[r] * -1.442695040888963f);
      const float Be = __builtin_amdgcn_exp2f(gI[r] * -1.442695040888963f);
      const float Ge = __builtin_amdgcn_exp2f(gG[r] * -2.885390081777927f);
      const float M1 = (1.0f + Be) * (1.0f + Ge);
      const float nm = cc[rr] * M1 + (1.0f - Ge) * (1.0f + Ae);
      cc[rr] = nm * __builtin_amdgcn_rcpf((1.0f + Ae) * M1);
      const float Oe = __builtin_amdgcn_exp2f(gO[r] * -1.442695040888963f);
      const float tc = 2.0f * __builtin_amdgcn_rcpf(
                         1.0f + __builtin_amdgcn_exp2f(cc[rr] * -2.885390081777927f)) - 1.0f;
      dst[hOff + r * S0] = f2bf(__builtin_amdgcn_rcpf(1.0f + Oe) * tc);
    }
  };

  unsigned short* H0 = &A0[0][0];    // after encoder: h0(1023) ++ x(1023)
  unsigned short* H1 = &A1[1][0];    // after encoder: h1(1023)

  if (isA) {
    // ================= layer-0 engine (waves 0-7) =================
    bf16x8 WA[12]; f32x4 bvA[4];
#pragma unroll
    for (int gt = 0; gt < 4; ++gt) {
      const int col = 64 * gt + u;
      WA[gt * 3 + 0] = ld8(Whh0v, col * HDIM + 8 * q);
      WA[gt * 3 + 1] = ld8(Whh0v, col * HDIM + 32 + 8 * q);
      union { unsigned short us[8]; bf16x8 v; } t2;
#pragma unroll
      for (int j = 0; j < 8; ++j) t2.us[j] = 0;
      if (q == 0) {
#pragma unroll
        for (int j = 0; j < INDIM; ++j) t2.us[j] = f2bf(ld1(Wih0v, col * INDIM + j));
      }
      WA[gt * 3 + 2] = t2.v;
      const float b = ld1(bih0v, col) + ld1(bhh0v, col);
      bvA[gt] = (f32x4){b, b, b, b};
    }

    int t0v = 0;
    for (int i = 0; i <= T_SEQ; ++i) {
      if (((i + 1) & (CHNK - 1)) == 0 && (i + 1) < T_SEQ) {
        load_chunk(i + 1);
        __syncthreads();
        t0v = i + 1;
      }
      const int cur = i & 1;
      if (i < T_SEQ) {
        const unsigned short* A0c = &A0[cur][0];
        unsigned short*       A0n = &A0[cur ^ 1][0];
        const bf16x8 f0 = *(const bf16x8*)(A0c + aOff);
        const bf16x8 f1 = *(const bf16x8*)(A0c + aOff + 32);
        const bf16x8 f2 = *(const bf16x8*)(A0c + aOff + 64);
        f32x4 g0 = MFMA16(f0, WA[0], bvA[0]); g0 = MFMA16(f1, WA[1],  g0); g0 = MFMA16(f2, WA[2],  g0);
        f32x4 g1 = MFMA16(f0, WA[3], bvA[1]); g1 = MFMA16(f1, WA[4],  g1); g1 = MFMA16(f2, WA[5],  g1);
        f32x4 g2 = MFMA16(f0, WA[6], bvA[2]); g2 = MFMA16(f1, WA[7],  g2); g2 = MFMA16(f2, WA[8],  g2);
        f32x4 g3 = MFMA16(f0, WA[9], bvA[3]); g3 = MFMA16(f1, WA[10], g3); g3 = MFMA16(f2, WA[11], g3);
        act2(g0, g1, g2, g3, A0n);
        const int srct = (i + 1 < T_SEQ) ? (i + 1) : (T_SEQ - 1);
        if (tid < 96) A0n[xWrOff] = XB[xbBase + (srct - t0v) * INDIM];
      }
      __syncthreads();
    }
    // decoder, engine A (4 barriers/step, mirrored in B)
    for (int d = 0; d < NPRED; ++d) {
      const bf16x8 fa0 = *(const bf16x8*)(H0 + aOff);
      const bf16x8 fa1 = *(const bf16x8*)(H0 + aOff + 32);
      const bf16x8 fa2 = *(const bf16x8*)(H0 + aOff + 64);
      __syncthreads();                      // ph1
      {
        f32x4 g0 = MFMA16(fa0, WA[0], bvA[0]); g0 = MFMA16(fa1, WA[1],  g0); g0 = MFMA16(fa2, WA[2],  g0);
        f32x4 g1 = MFMA16(fa0, WA[3], bvA[1]); g1 = MFMA16(fa1, WA[4],  g1); g1 = MFMA16(fa2, WA[5],  g1);
        f32x4 g2 = MFMA16(fa0, WA[6], bvA[2]); g2 = MFMA16(fa1, WA[7],  g2); g2 = MFMA16(fa2, WA[8],  g2);
        f32x4 g3 = MFMA16(fa0, WA[9], bvA[3]); g3 = MFMA16(fa1, WA[10], g3); g3 = MFMA16(fa2, WA[11], g3);
        act2(g0, g1, g2, g3, H0);
      }
      __syncthreads();                      // ph2
      __syncthreads();                      // ph3 (B computes h1)
      if (tid < 96) {                       // ph4: FC head + feedback
        const unsigned short* h1row = H1 + xrow * S0;
        const int4* hp = (const int4*)h1row;
        const int4* wp = (const int4*)(&FCW[xk * HDIM]);
        float s = FCB[xk];
#pragma unroll
        for (int i8 = 0; i8 < 8; ++i8) {
          const int4 hv = hp[i8];
          const int4 wv2 = wp[i8];
          const unsigned int hu[4] = {(unsigned)hv.x, (unsigned)hv.y, (unsigned)hv.z, (unsigned)hv.w};
          const unsigned int wu[4] = {(unsigned)wv2.x, (unsigned)wv2.y, (unsigned)wv2.z, (unsigned)wv2.w};
#pragma unroll
          for (int k2 = 0; k2 < 4; ++k2) {
            union { unsigned int uu; float ff; } hl, hh2, wl, wh;
            hl.uu = hu[k2] << 16; hh2.uu = hu[k2] & 0xFFFF0000u;
            wl.uu = wu[k2] << 16; wh.uu  = wu[k2] & 0xFFFF0000u;
            s += hl.ff * wl.ff + hh2.ff * wh.ff;
          }
        }
        const unsigned short pb = f2bf(s);
        const size_t idx = (size_t)(rbase + xrow) * (NPRED * INDIM) + (size_t)d * INDIM + xk;
        if constexpr (F32) ((float*)outv)[idx] = s;
        else               ((unsigned short*)outv)[idx] = pb;
        H0[xWrOff] = pb;
      }
      __syncthreads();                      // ph4 end
    }
  } else {
    // ================= layer-1 engine (waves 8-15, lag 1) =================
    bf16x8 WB[16]; f32x4 bvB[4];
#pragma unroll
    for (int gt = 0; gt < 4; ++gt) {
      const int col = 64 * gt + u;
      WB[gt * 4 + 0] = ld8(Wih1v, col * HDIM + 8 * q);
      WB[gt * 4 + 1] = ld8(Wih1v, col * HDIM + 32 + 8 * q);
      WB[gt * 4 + 2] = ld8(Whh1v, col * HDIM + 8 * q);
      WB[gt * 4 + 3] = ld8(Whh1v, col * HDIM + 32 + 8 * q);
      const float b = ld1(bih1v, col) + ld1(bhh1v, col);
      bvB[gt] = (f32x4){b, b, b, b};
    }

    for (int i = 0; i <= T_SEQ; ++i) {
      if (((i + 1) & (CHNK - 1)) == 0 && (i + 1) < T_SEQ) {
        load_chunk(i + 1);
        __syncthreads();
      }
      const int cur = i & 1;
      if (i >= 1) {
        const unsigned short* A0c = &A0[cur][0];
        const unsigned short* A1c = &A1[cur][0];
        unsigned short*       A1n = &A1[cur ^ 1][0];
        const bf16x8 h0a = *(const bf16x8*)(A0c + aOff);
        const bf16x8 h0b = *(const bf16x8*)(A0c + aOff + 32);
        const bf16x8 r0  = *(const bf16x8*)(A1c + aOff);
        const bf16x8 r1  = *(const bf16x8*)(A1c + aOff + 32);
        f32x4 g0 = MFMA16(h0a, WB[0],  bvB[0]); g0 = MFMA16(h0b, WB[1],  g0); g0 = MFMA16(r0, WB[2],  g0); g0 = MFMA16(r1, WB[3],  g0);
        f32x4 g1 = MFMA16(h0a, WB[4],  bvB[1]); g1 = MFMA16(h0b, WB[5],  g1); g1 = MFMA16(r0, WB[6],  g1); g1 = MFMA16(r1, WB[7],  g1);
        f32x4 g2 = MFMA16(h0a, WB[8],  bvB[2]); g2 = MFMA16(h0b, WB[9],  g2); g2 = MFMA16(r0, WB[10], g2); g2 = MFMA16(r1, WB[11], g2);
        f32x4 g3 = MFMA16(h0a, WB[12], bvB[3]); g3 = MFMA16(h0b, WB[13], g3); g3 = MFMA16(r0, WB[14], g3); g3 = MFMA16(r1, WB[15], g3);
        act2(g0, g1, g2, g3, A1n);
      }
      __syncthreads();
    }
    // decoder, engine B (4 barriers/step, mirrored with A)
    for (int d = 0; d < NPRED; ++d) {
      const bf16x8 fr0 = *(const bf16x8*)(H1 + aOff);
      const bf16x8 fr1 = *(const bf16x8*)(H1 + aOff + 32);
      __syncthreads();                      // ph1
      __syncthreads();                      // ph2 (A computes h0)
      {
        const bf16x8 h0a = *(const bf16x8*)(H0 + aOff);
        const bf16x8 h0b = *(const bf16x8*)(H0 + aOff + 32);
        f32x4 g0 = MFMA16(h0a, WB[0],  bvB[0]); g0 = MFMA16(h0b, WB[1],  g0); g0 = MFMA16(fr0, WB[2],  g0); g0 = MFMA16(fr1, WB[3],  g0);
        f32x4 g1 = MFMA16(h0a, WB[4],  bvB[1]); g1 = MFMA16(h0b, WB[5],  g1); g1 = MFMA16(fr0, WB[6],  g1); g1 = MFMA16(fr1, WB[7],  g1);
        f32x4 g2 = MFMA16(h0a, WB[8],  bvB[2]); g2 = MFMA16(h0b, WB[9],  g2); g2 = MFMA16(fr0, WB[10], g2); g2 = MFMA16(fr1, WB[11], g2);
        f32x4 g3 = MFMA16(h0a, WB[12], bvB[3]); g3 = MFMA16(h0b, WB[13], g3); g3 = MFMA16(fr0, WB[14], g3); g3 = MFMA16(fr1, WB[15], g3);
        act2(g0, g1, g2, g3, H1);
      }
      __syncthreads();                      // ph3
      __syncthreads();                      // ph4 (A does FC head)
    }
  }
}

extern "C" void kernel_launch(void* const* d_in, const int* in_sizes, int n_in,
                              void* d_out, int out_size, void* d_ws, size_t ws_size,
                              hipStream_t stream) {
  (void)in_sizes; (void)n_in; (void)d_ws; (void)ws_size; (void)out_size;
  const void* x    = d_in[0];
  const void* Wih0 = d_in[1];
  const void* Whh0 = d_in[2];
  const void* bih0 = d_in[3];
  const void* bhh0 = d_in[4];
  const void* Wih1 = d_in[5];
  const void* Whh1 = d_in[6];
  const void* bih1 = d_in[7];
  const void* bhh1 = d_in[8];
  const void* fcw  = d_in[9];
  const void* fcb  = d_in[10];
  // Exactly one instance does the work (device-side dtype sniff).
  lstm2_pipe<true><<<dim3(4096 / NROWS), dim3(1024), 0, stream>>>(
      x, Wih0, Whh0, bih0, bhh0, Wih1, Whh1, bih1, bhh1, fcw, fcb, d_out);
  lstm2_pipe<false><<<dim3(4096 / NROWS), dim3(1024), 0, stream>>>(
      x, Wih0, Whh0, bih0, bhh0, Wih1, Whh1, bih1, bhh1, fcw, fcb, d_out);
}

// Round 13
// 920.960 us; speedup vs baseline: 1.3561x; 1.3561x over previous
//
#include <hip/hip_runtime.h>

#define T_SEQ   1024
#define INDIM   6
#define HDIM    64
#define NPRED   10
#define CHNK    128
#define S0      104      // LDS row stride (elements) for h/x buffers
#define NROWS   16       // batch rows per workgroup (grid 256 = 1 block/CU)

typedef __bf16         bf16x8 __attribute__((ext_vector_type(8)));
typedef float          f32x4  __attribute__((ext_vector_type(4)));
typedef unsigned short us4    __attribute__((ext_vector_type(4)));

// D = A*B + C with A = weight frag, B = h frag  ->  D[m=unit][n=batch row]
#define MFMA16(a, b, c) __builtin_amdgcn_mfma_f32_16x16x32_bf16((a), (b), (c), 0, 0, 0)

static __device__ __forceinline__ float bf2f(unsigned short b) {
  union { unsigned int u; float f; } v; v.u = ((unsigned int)b) << 16; return v.f;
}
static __device__ __forceinline__ unsigned short f2bf(float f) {
  union { float f; unsigned int u; } v; v.f = f;
  unsigned int r = v.u + 0x7FFFu + ((v.u >> 16) & 1u);
  return (unsigned short)(r >> 16);
}

// r11 skeleton (layer-pipelined, 1 barrier/encoder step, 512 thr, 2 waves/SIMD)
// with TRANSPOSED MFMA: W as A-operand, h as B-operand. Per-lane load bytes are
// identical to r11 (A/B frag layouts are mutual transposes); D comes out as
// [unit][row], so each lane's 4 cells are 4 CONSECUTIVE units of one row ->
// h-write is one packed ds_write_b64 (2-way banks, free) instead of 4 scalar
// b16 writes. Bias C-init becomes a vector load. 7 trans/cell (o/tanh fused).
template <bool F32>
__global__ __launch_bounds__(512, 2)
void lstm2_pipe(const void* __restrict__ xv,
                const void* __restrict__ Wih0v,
                const void* __restrict__ Whh0v,
                const void* __restrict__ bih0v,
                const void* __restrict__ bhh0v,
                const void* __restrict__ Wih1v,
                const void* __restrict__ Whh1v,
                const void* __restrict__ bih1v,
                const void* __restrict__ bhh1v,
                const void* __restrict__ fcwv,
                const void* __restrict__ fcbv,
                void* __restrict__ outv)
{
  // ---- dtype sniff (uniform) ----
  {
    const unsigned short* w0u = (const unsigned short*)Wih0v;
    int votes = 0;
#pragma unroll
    for (int i = 0; i < 16; ++i) {
      const unsigned e = (w0u[2 * i] >> 7) & 0xFF;
      votes += (e >= 0x80 || e <= 0x40) ? 1 : 0;
    }
    if ((votes >= 4) != F32) return;
  }

  // A0[b]: [row][k]: k 0..63 = h0 (unit-major), 64..69 = x, 70..95 zero pad.
  __shared__ __align__(16) unsigned short A0[2][NROWS * S0];
  __shared__ __align__(16) unsigned short A1[2][NROWS * S0];
  __shared__ __align__(16) unsigned short XB[NROWS * CHNK * INDIM];
  __shared__ __align__(16) unsigned short FCW[INDIM * HDIM];
  __shared__ float FCB[INDIM];

  const int tid   = threadIdx.x;
  const int lane  = tid & 63;
  const int wave  = tid >> 6;
  const bool isA  = (wave < 4);
  const int  wv4  = wave & 3;
  const int  q    = lane >> 4;
  const int  n    = lane & 15;          // batch row owned by this lane (D col)
  const int  u    = 16 * wv4 + n;       // index used for W/bias row addressing
  const int rbase = blockIdx.x * NROWS;

  {
    unsigned short* p0 = &A0[0][0];
    unsigned short* p1 = &A1[0][0];
    for (int i = tid; i < 2 * NROWS * S0; i += 512) { p0[i] = 0; p1[i] = 0; }
  }
  for (int i = tid; i < INDIM * HDIM; i += 512) {
    if constexpr (F32) FCW[i] = f2bf(((const float*)fcwv)[i]);
    else               FCW[i] = ((const unsigned short*)fcwv)[i];
  }
  if (tid < INDIM) {
    if constexpr (F32) FCB[tid] = ((const float*)fcbv)[tid];
    else               FCB[tid] = bf2f(((const unsigned short*)fcbv)[tid]);
  }

  auto ld1 = [&](const void* p, int i) -> float {
    if constexpr (F32) return ((const float*)p)[i];
    else               return bf2f(((const unsigned short*)p)[i]);
  };
  auto ld8 = [&](const void* W, int off) -> bf16x8 {
    union { unsigned short us[8]; bf16x8 v; } t;
    if constexpr (F32) {
      const float* p = (const float*)W + off;
#pragma unroll
      for (int j = 0; j < 8; ++j) t.us[j] = f2bf(p[j]);
    } else {
      t.v = *(const bf16x8*)((const unsigned short*)W + off);
    }
    return t.v;
  };

  auto load_chunk = [&](int t0c) {
    if constexpr (F32) {
      const char* xb = (const char*)xv;
      for (int c = tid; c < NROWS * 192; c += 512) {
        const int row = c / 192;
        const int off = c - row * 192;
        const float4 v = *(const float4*)(xb + (size_t)(rbase + row) * (T_SEQ * INDIM * 4)
                                             + (size_t)t0c * (INDIM * 4) + (size_t)off * 16);
        us4 o;
        o.x = f2bf(v.x); o.y = f2bf(v.y); o.z = f2bf(v.z); o.w = f2bf(v.w);
        *(us4*)((char*)XB + (size_t)c * 8) = o;
      }
    } else {
      const char* xb = (const char*)xv;
      for (int c = tid; c < NROWS * 96; c += 512) {
        const int row = c / 96;
        const int off = c - row * 96;
        const int4 v = *(const int4*)(xb + (size_t)(rbase + row) * (T_SEQ * INDIM * 2)
                                         + (size_t)t0c * (INDIM * 2) + (size_t)off * 16);
        *(int4*)((char*)XB + (size_t)c * 16) = v;
      }
    }
  };

  load_chunk(0);
  __syncthreads();

  const int xrow   = tid / INDIM;                 // valid for tid < 96 (A waves)
  const int xk     = tid - xrow * INDIM;
  const int xWrOff = xrow * S0 + HDIM + xk;
  const int xbBase = xrow * (CHNK * INDIM) + xk;

  if (tid < 96) A0[0][xWrOff] = XB[xbBase];       // x_0
  __syncthreads();

  const int aOff  = n * S0 + 8 * q;               // h frag (B-operand): row n, k 8q..
  const int hOffW = n * S0 + 16 * wv4 + 4 * q;    // packed h-write: row n, units 4q..4q+3
  const int bOff  = 16 * wv4 + 4 * q;             // bias vector base within gate block

  float cc[4] = {0.f, 0.f, 0.f, 0.f};  // 4 cells: units 16wv4+4q+r, row n

  // bias vector for gate block gt: b[64gt + bOff .. +3]
  auto ldbias = [&](const void* b1, const void* b2, int gt) -> f32x4 {
    f32x4 r;
#pragma unroll
    for (int j = 0; j < 4; ++j)
      r[j] = ld1(b1, 64 * gt + bOff + j) + ld1(b2, 64 * gt + bOff + j);
    return r;
  };

  // 7-trans combined-rcp cell update + packed b64 h-write.
  auto act4 = [&](const f32x4 gI, const f32x4 gF, const f32x4 gG, const f32x4 gO,
                  unsigned short* dst) {
    unsigned short hb[4];
#pragma unroll
    for (int r = 0; r < 4; ++r) {
      const float Ae = __builtin_amdgcn_exp2f(gF[r] * -1.442695040888963f);
      const float Be = __builtin_amdgcn_exp2f(gI[r] * -1.442695040888963f);
      const float Ge = __builtin_amdgcn_exp2f(gG[r] * -2.885390081777927f);
      const float M1 = (1.0f + Be) * (1.0f + Ge);
      const float nm = cc[r] * M1 + (1.0f - Ge) * (1.0f + Ae);
      cc[r] = nm * __builtin_amdgcn_rcpf((1.0f + Ae) * M1);
      const float Oe = __builtin_amdgcn_exp2f(gO[r] * -1.442695040888963f);
      const float Ee = __builtin_amdgcn_exp2f(cc[r] * -2.885390081777927f);
      hb[r] = f2bf((1.0f - Ee) * __builtin_amdgcn_rcpf((1.0f + Ee) * (1.0f + Oe)));
    }
    const unsigned int lo = (unsigned int)hb[0] | ((unsigned int)hb[1] << 16);
    const unsigned int hi = (unsigned int)hb[2] | ((unsigned int)hb[3] << 16);
    uint2 pk; pk.x = lo; pk.y = hi;
    *(uint2*)(dst + hOffW) = pk;
  };

  unsigned short* H0 = &A0[0][0];    // after encoder: h0(1023) ++ x(1023)
  unsigned short* H1 = &A1[1][0];    // after encoder: h1(1023)

  if (isA) {
    // ================= layer-0 engine =================
    bf16x8 WA[12]; f32x4 bvA[4];
#pragma unroll
    for (int gt = 0; gt < 4; ++gt) {
      const int col = 64 * gt + u;
      WA[gt * 3 + 0] = ld8(Whh0v, col * HDIM + 8 * q);       // A-frag: W[unit][k]
      WA[gt * 3 + 1] = ld8(Whh0v, col * HDIM + 32 + 8 * q);
      union { unsigned short us[8]; bf16x8 v; } t2;
#pragma unroll
      for (int j = 0; j < 8; ++j) t2.us[j] = 0;
      if (q == 0) {
#pragma unroll
        for (int j = 0; j < INDIM; ++j) t2.us[j] = f2bf(ld1(Wih0v, col * INDIM + j));
      }
      WA[gt * 3 + 2] = t2.v;
      bvA[gt] = ldbias(bih0v, bhh0v, gt);
    }

    int t0v = 0;
    for (int i = 0; i <= T_SEQ; ++i) {
      if (((i + 1) & (CHNK - 1)) == 0 && (i + 1) < T_SEQ) {
        load_chunk(i + 1);
        __syncthreads();
        t0v = i + 1;
      }
      const int cur = i & 1;
      if (i < T_SEQ) {
        const unsigned short* A0c = &A0[cur][0];
        unsigned short*       A0n = &A0[cur ^ 1][0];
        const bf16x8 f0 = *(const bf16x8*)(A0c + aOff);
        const bf16x8 f1 = *(const bf16x8*)(A0c + aOff + 32);
        const bf16x8 f2 = *(const bf16x8*)(A0c + aOff + 64);
        f32x4 g0 = MFMA16(WA[0], f0, bvA[0]); g0 = MFMA16(WA[1],  f1, g0); g0 = MFMA16(WA[2],  f2, g0);
        f32x4 g1 = MFMA16(WA[3], f0, bvA[1]); g1 = MFMA16(WA[4],  f1, g1); g1 = MFMA16(WA[5],  f2, g1);
        f32x4 g2 = MFMA16(WA[6], f0, bvA[2]); g2 = MFMA16(WA[7],  f1, g2); g2 = MFMA16(WA[8],  f2, g2);
        f32x4 g3 = MFMA16(WA[9], f0, bvA[3]); g3 = MFMA16(WA[10], f1, g3); g3 = MFMA16(WA[11], f2, g3);
        act4(g0, g1, g2, g3, A0n);
        const int srct = (i + 1 < T_SEQ) ? (i + 1) : (T_SEQ - 1);
        if (tid < 96) A0n[xWrOff] = XB[xbBase + (srct - t0v) * INDIM];
      }
      __syncthreads();
    }
    // decoder, engine A (4 barriers/step, mirrored in B)
    for (int d = 0; d < NPRED; ++d) {
      const bf16x8 fa0 = *(const bf16x8*)(H0 + aOff);
      const bf16x8 fa1 = *(const bf16x8*)(H0 + aOff + 32);
      const bf16x8 fa2 = *(const bf16x8*)(H0 + aOff + 64);
      __syncthreads();                      // ph1
      {
        f32x4 g0 = MFMA16(WA[0], fa0, bvA[0]); g0 = MFMA16(WA[1],  fa1, g0); g0 = MFMA16(WA[2],  fa2, g0);
        f32x4 g1 = MFMA16(WA[3], fa0, bvA[1]); g1 = MFMA16(WA[4],  fa1, g1); g1 = MFMA16(WA[5],  fa2, g1);
        f32x4 g2 = MFMA16(WA[6], fa0, bvA[2]); g2 = MFMA16(WA[7],  fa1, g2); g2 = MFMA16(WA[8],  fa2, g2);
        f32x4 g3 = MFMA16(WA[9], fa0, bvA[3]); g3 = MFMA16(WA[10], fa1, g3); g3 = MFMA16(WA[11], fa2, g3);
        act4(g0, g1, g2, g3, H0);
      }
      __syncthreads();                      // ph2
      __syncthreads();                      // ph3 (B computes h1)
      if (tid < 96) {                       // ph4: FC head + feedback
        const unsigned short* h1row = H1 + xrow * S0;
        const int4* hp = (const int4*)h1row;
        const int4* wp = (const int4*)(&FCW[xk * HDIM]);
        float s = FCB[xk];
#pragma unroll
        for (int i8 = 0; i8 < 8; ++i8) {
          const int4 hv = hp[i8];
          const int4 wv2 = wp[i8];
          const unsigned int hu[4] = {(unsigned)hv.x, (unsigned)hv.y, (unsigned)hv.z, (unsigned)hv.w};
          const unsigned int wu[4] = {(unsigned)wv2.x, (unsigned)wv2.y, (unsigned)wv2.z, (unsigned)wv2.w};
#pragma unroll
          for (int k2 = 0; k2 < 4; ++k2) {
            union { unsigned int uu; float ff; } hl, hh2, wl, wh;
            hl.uu = hu[k2] << 16; hh2.uu = hu[k2] & 0xFFFF0000u;
            wl.uu = wu[k2] << 16; wh.uu  = wu[k2] & 0xFFFF0000u;
            s += hl.ff * wl.ff + hh2.ff * wh.ff;
          }
        }
        const unsigned short pb = f2bf(s);
        const size_t idx = (size_t)(rbase + xrow) * (NPRED * INDIM) + (size_t)d * INDIM + xk;
        if constexpr (F32) ((float*)outv)[idx] = s;
        else               ((unsigned short*)outv)[idx] = pb;
        H0[xWrOff] = pb;
      }
      __syncthreads();                      // ph4 end
    }
  } else {
    // ================= layer-1 engine (lag 1) =================
    bf16x8 WB[16]; f32x4 bvB[4];
#pragma unroll
    for (int gt = 0; gt < 4; ++gt) {
      const int col = 64 * gt + u;
      WB[gt * 4 + 0] = ld8(Wih1v, col * HDIM + 8 * q);
      WB[gt * 4 + 1] = ld8(Wih1v, col * HDIM + 32 + 8 * q);
      WB[gt * 4 + 2] = ld8(Whh1v, col * HDIM + 8 * q);
      WB[gt * 4 + 3] = ld8(Whh1v, col * HDIM + 32 + 8 * q);
      bvB[gt] = ldbias(bih1v, bhh1v, gt);
    }

    for (int i = 0; i <= T_SEQ; ++i) {
      if (((i + 1) & (CHNK - 1)) == 0 && (i + 1) < T_SEQ) {
        load_chunk(i + 1);
        __syncthreads();
      }
      const int cur = i & 1;
      if (i >= 1) {
        const unsigned short* A0c = &A0[cur][0];
        const unsigned short* A1c = &A1[cur][0];
        unsigned short*       A1n = &A1[cur ^ 1][0];
        const bf16x8 h0a = *(const bf16x8*)(A0c + aOff);
        const bf16x8 h0b = *(const bf16x8*)(A0c + aOff + 32);
        const bf16x8 r0  = *(const bf16x8*)(A1c + aOff);
        const bf16x8 r1  = *(const bf16x8*)(A1c + aOff + 32);
        f32x4 g0 = MFMA16(WB[0],  h0a, bvB[0]); g0 = MFMA16(WB[1],  h0b, g0); g0 = MFMA16(WB[2],  r0, g0); g0 = MFMA16(WB[3],  r1, g0);
        f32x4 g1 = MFMA16(WB[4],  h0a, bvB[1]); g1 = MFMA16(WB[5],  h0b, g1); g1 = MFMA16(WB[6],  r0, g1); g1 = MFMA16(WB[7],  r1, g1);
        f32x4 g2 = MFMA16(WB[8],  h0a, bvB[2]); g2 = MFMA16(WB[9],  h0b, g2); g2 = MFMA16(WB[10], r0, g2); g2 = MFMA16(WB[11], r1, g2);
        f32x4 g3 = MFMA16(WB[12], h0a, bvB[3]); g3 = MFMA16(WB[13], h0b, g3); g3 = MFMA16(WB[14], r0, g3); g3 = MFMA16(WB[15], r1, g3);
        act4(g0, g1, g2, g3, A1n);
      }
      __syncthreads();
    }
    // decoder, engine B (4 barriers/step, mirrored with A)
    for (int d = 0; d < NPRED; ++d) {
      const bf16x8 fr0 = *(const bf16x8*)(H1 + aOff);
      const bf16x8 fr1 = *(const bf16x8*)(H1 + aOff + 32);
      __syncthreads();                      // ph1
      __syncthreads();                      // ph2 (A computes h0)
      {
        const bf16x8 h0a = *(const bf16x8*)(H0 + aOff);
        const bf16x8 h0b = *(const bf16x8*)(H0 + aOff + 32);
        f32x4 g0 = MFMA16(WB[0],  h0a, bvB[0]); g0 = MFMA16(WB[1],  h0b, g0); g0 = MFMA16(WB[2],  fr0, g0); g0 = MFMA16(WB[3],  fr1, g0);
        f32x4 g1 = MFMA16(WB[4],  h0a, bvB[1]); g1 = MFMA16(WB[5],  h0b, g1); g1 = MFMA16(WB[6],  fr0, g1); g1 = MFMA16(WB[7],  fr1, g1);
        f32x4 g2 = MFMA16(WB[8],  h0a, bvB[2]); g2 = MFMA16(WB[9],  h0b, g2); g2 = MFMA16(WB[10], fr0, g2); g2 = MFMA16(WB[11], fr1, g2);
        f32x4 g3 = MFMA16(WB[12], h0a, bvB[3]); g3 = MFMA16(WB[13], h0b, g3); g3 = MFMA16(WB[14], fr0, g3); g3 = MFMA16(WB[15], fr1, g3);
        act4(g0, g1, g2, g3, H1);
      }
      __syncthreads();                      // ph3
      __syncthreads();                      // ph4 (A does FC head)
    }
  }
}

extern "C" void kernel_launch(void* const* d_in, const int* in_sizes, int n_in,
                              void* d_out, int out_size, void* d_ws, size_t ws_size,
                              hipStream_t stream) {
  (void)in_sizes; (void)n_in; (void)d_ws; (void)ws_size; (void)out_size;
  const void* x    = d_in[0];
  const void* Wih0 = d_in[1];
  const void* Whh0 = d_in[2];
  const void* bih0 = d_in[3];
  const void* bhh0 = d_in[4];
  const void* Wih1 = d_in[5];
  const void* Whh1 = d_in[6];
  const void* bih1 = d_in[7];
  const void* bhh1 = d_in[8];
  const void* fcw  = d_in[9];
  const void* fcb  = d_in[10];
  // Exactly one instance does the work (device-side dtype sniff).
  lstm2_pipe<true><<<dim3(4096 / NROWS), dim3(512), 0, stream>>>(
      x, Wih0, Whh0, bih0, bhh0, Wih1, Whh1, bih1, bhh1, fcw, fcb, d_out);
  lstm2_pipe<false><<<dim3(4096 / NROWS), dim3(512), 0, stream>>>(
      x, Wih0, Whh0, bih0, bhh0, Wih1, Whh1, bih1, bhh1, fcw, fcb, d_out);
}